// Round 2
// baseline (130.393 us; speedup 1.0000x reference)
//
#include <hip/hip_runtime.h>
#include <stdint.h>

#define N_NODES 8192
#define NE      131072
#define D       128
#define WPR     256            // bitmap words per row = N/32
#define EPS     1e-5f

// ---------------------------------------------------------------------------
// Detect whether edge_index buffer is int64 (reference dtype) or int32
// (harness may narrow). If any value read as int64 is outside [0,N), the
// buffer must be int32-packed (high word of a pair is a node id != 0).
// flag=1 -> int32. Parallel: 128 blocks, ballot-reduced atomicOr.
__global__ __launch_bounds__(256) void detect_idx_kernel(const long long* __restrict__ ei,
                                                         int* __restrict__ flag) {
    int bad = 0;
    for (size_t i = blockIdx.x * blockDim.x + threadIdx.x; i < NE;
         i += (size_t)gridDim.x * blockDim.x) {
        if ((unsigned long long)ei[i] >= (unsigned long long)N_NODES) bad = 1;
    }
    if (__any(bad) && (threadIdx.x & 63) == 0) atomicOr(flag, 1);
}

// ---------------------------------------------------------------------------
// Build symmetric adjacency bitmap: set bit (r,c) and (c,r).
// Bit-set is idempotent -> duplicate edges collapse (matches .at[].set(1.0)),
// and setting both directions == max(A, A^T).
__global__ __launch_bounds__(256) void edge_bitmap_kernel(const void* __restrict__ ei_raw,
                                                          const int* __restrict__ flag,
                                                          uint32_t* __restrict__ bm) {
    int e = blockIdx.x * blockDim.x + threadIdx.x;
    if (e >= NE) return;
    int r, c;
    if (*flag) {
        const int* p = (const int*)ei_raw;
        r = p[e]; c = p[NE + e];
    } else {
        const long long* p = (const long long*)ei_raw;
        r = (int)p[e]; c = (int)p[NE + e];
    }
    atomicOr(&bm[(size_t)r * WPR + (c >> 5)], 1u << (c & 31));
    atomicOr(&bm[(size_t)c * WPR + (r >> 5)], 1u << (r & 31));
}

// ---------------------------------------------------------------------------
// Degree per node = popcount(bitmap row) + 1 (the +I). A self-edge bit is
// already in the popcount, making its diagonal weight 2 — matches reference.
// One wave per node, uint4 row loads, shuffle reduce.
__global__ __launch_bounds__(256) void degree_kernel(const uint4* __restrict__ bm4,
                                                     float* __restrict__ dinv) {
    int wave = threadIdx.x >> 6;
    int lane = threadIdx.x & 63;
    int node = blockIdx.x * 4 + wave;
    uint4 w = bm4[(size_t)node * 64 + lane];   // 64 lanes x 16B = 1KB row
    int cnt = __popc(w.x) + __popc(w.y) + __popc(w.z) + __popc(w.w);
    #pragma unroll
    for (int off = 32; off; off >>= 1) cnt += __shfl_down(cnt, off);
    if (lane == 0) dinv[node] = 1.0f / sqrtf((float)cnt + 1.0f + EPS);
}

// ---------------------------------------------------------------------------
// agg[i][t] = dinv[i] * ( sum_{j in bitmap row i} dinv[j]*x[j][t] + dinv[i]*x[i][t] )
// One block (128 threads = 128 channels) per node. Neighbor list compacted
// into LDS, then unroll-by-2 neighbor loop (dual accumulators) to keep two
// x-row loads in flight and halve exposed L2/L3 latency.
__global__ __launch_bounds__(128) void aggregate_kernel(const uint32_t* __restrict__ bm,
                                                        const float* __restrict__ x,
                                                        const float* __restrict__ dinv,
                                                        float* __restrict__ agg) {
    __shared__ uint16_t s_list[N_NODES];
    __shared__ int s_cnt;
    int node = blockIdx.x;
    int t = threadIdx.x;
    if (t == 0) s_cnt = 0;
    __syncthreads();

    // scan 2 words (64 bits) per thread, compact set bits into LDS list
    uint32_t w0 = bm[(size_t)node * WPR + 2 * t];
    uint32_t w1 = bm[(size_t)node * WPR + 2 * t + 1];
    int local = __popc(w0) + __popc(w1);
    int base = 0;
    if (local) base = atomicAdd(&s_cnt, local);
    int jbase = t * 64;
    while (w0) { int b = __ffs(w0) - 1; w0 &= w0 - 1; s_list[base++] = (uint16_t)(jbase + b); }
    while (w1) { int b = __ffs(w1) - 1; w1 &= w1 - 1; s_list[base++] = (uint16_t)(jbase + 32 + b); }
    __syncthreads();

    int cnt = s_cnt;
    float di = dinv[node];
    float acc0 = di * x[(size_t)node * D + t];   // identity (+I) contribution
    float acc1 = 0.0f;
    int k = 0;
    for (; k + 2 <= cnt; k += 2) {
        int j0 = __builtin_amdgcn_readfirstlane((int)s_list[k]);
        int j1 = __builtin_amdgcn_readfirstlane((int)s_list[k + 1]);
        float d0 = dinv[j0], d1 = dinv[j1];
        float x0 = x[(size_t)j0 * D + t];
        float x1 = x[(size_t)j1 * D + t];
        acc0 += d0 * x0;
        acc1 += d1 * x1;
    }
    if (k < cnt) {
        int j = __builtin_amdgcn_readfirstlane((int)s_list[k]);
        acc0 += dinv[j] * x[(size_t)j * D + t];
    }
    agg[(size_t)node * D + t] = di * (acc0 + acc1);
}

// ---------------------------------------------------------------------------
// out = agg @ W + bias.  f32 vector GEMM (no fp32 MFMA on CDNA4).
// 64x64 tile per block, 256 threads, 4x4 per thread. A tile in LDS (padded),
// W (64KB total) read through L1/L2.
__global__ __launch_bounds__(256) void gemm_kernel(const float* __restrict__ A,
                                                   const float* __restrict__ W,
                                                   const float* __restrict__ bias,
                                                   float* __restrict__ out) {
    __shared__ float sA[64][132];   // +4 pad: 16B-aligned rows, conflict-free reads
    int t = threadIdx.x;
    int row0 = blockIdx.x * 64;
    int col0 = blockIdx.y * 64;

    {   // load 64x128 A tile, float4 per thread x 8 passes, coalesced
        int k4 = t & 31;
        int r  = t >> 5;
        #pragma unroll
        for (int p = 0; p < 8; ++p) {
            float4 v = *(const float4*)&A[(size_t)(row0 + r + p * 8) * D + k4 * 4];
            *(float4*)&sA[r + p * 8][k4 * 4] = v;
        }
    }
    __syncthreads();

    int tx = t & 15, ty = t >> 4;
    int cg = col0 + tx * 4;      // global col of this thread's 4 cols
    int r0 = ty * 4;             // local row base
    float acc[4][4] = {};

    #pragma unroll 4
    for (int k = 0; k < 128; ++k) {
        float4 w = *(const float4*)&W[(size_t)k * D + cg];
        float a0 = sA[r0 + 0][k];
        float a1 = sA[r0 + 1][k];
        float a2 = sA[r0 + 2][k];
        float a3 = sA[r0 + 3][k];
        acc[0][0] += a0 * w.x; acc[0][1] += a0 * w.y; acc[0][2] += a0 * w.z; acc[0][3] += a0 * w.w;
        acc[1][0] += a1 * w.x; acc[1][1] += a1 * w.y; acc[1][2] += a1 * w.z; acc[1][3] += a1 * w.w;
        acc[2][0] += a2 * w.x; acc[2][1] += a2 * w.y; acc[2][2] += a2 * w.z; acc[2][3] += a2 * w.w;
        acc[3][0] += a3 * w.x; acc[3][1] += a3 * w.y; acc[3][2] += a3 * w.z; acc[3][3] += a3 * w.w;
    }

    float4 b = *(const float4*)&bias[cg];
    #pragma unroll
    for (int i = 0; i < 4; ++i) {
        float4 o;
        o.x = acc[i][0] + b.x;
        o.y = acc[i][1] + b.y;
        o.z = acc[i][2] + b.z;
        o.w = acc[i][3] + b.w;
        *(float4*)&out[(size_t)(row0 + r0 + i) * D + cg] = o;
    }
}

// ---------------------------------------------------------------------------
extern "C" void kernel_launch(void* const* d_in, const int* in_sizes, int n_in,
                              void* d_out, int out_size, void* d_ws, size_t ws_size,
                              hipStream_t stream) {
    const float*     x    = (const float*)d_in[0];
    const void*      ei   = d_in[1];
    const float*     W    = (const float*)d_in[2];
    const float*     bias = (const float*)d_in[3];
    float*           out  = (float*)d_out;

    uint8_t* ws = (uint8_t*)d_ws;
    uint32_t* bm   = (uint32_t*)ws;                                      // 8 MB
    float*    dinv = (float*)(ws + (size_t)8 * 1024 * 1024);             // 32 KB
    float*    agg  = (float*)(ws + (size_t)8 * 1024 * 1024 + 32 * 1024); // 4 MB
    int*      flag = (int*)(ws + (size_t)8 * 1024 * 1024 + 32 * 1024 + (size_t)4 * 1024 * 1024);

    hipMemsetAsync(bm, 0, (size_t)N_NODES * WPR * sizeof(uint32_t), stream);
    hipMemsetAsync(flag, 0, sizeof(int), stream);
    detect_idx_kernel<<<128, 256, 0, stream>>>((const long long*)ei, flag);
    edge_bitmap_kernel<<<NE / 256, 256, 0, stream>>>(ei, flag, bm);
    degree_kernel<<<N_NODES / 4, 256, 0, stream>>>((const uint4*)bm, dinv);
    aggregate_kernel<<<N_NODES, 128, 0, stream>>>(bm, x, dinv, agg);
    gemm_kernel<<<dim3(N_NODES / 64, 2), 256, 0, stream>>>(agg, W, bias, out);
}